// Round 6
// baseline (444.370 us; speedup 1.0000x reference)
//
#include <hip/hip_runtime.h>
#include <stdint.h>

// ---- problem constants ----
#define BT   6272      // B*T = 32*196
#define LAT  256
#define NJ3  13
#define NJ2  10
#define NJ1  20
#define NJ   43
#define D3   39
#define D2   20
#define XDIM 79        // D3+D2+D1
#define OUTROW 11008   // NJ*LAT
#define NWG  (NJ * 98) // 4214 blocks in motion_main

typedef _Float16 half8  __attribute__((ext_vector_type(8)));
typedef _Float16 half4v __attribute__((ext_vector_type(4)));
typedef float    floatx4 __attribute__((ext_vector_type(4)));

// tanh-approx gelu (matches jax.nn.gelu default approximate=True)
// gelu(h) = h - h/(exp(2u)+1), 2u = h*(1.5957691 + 0.0713548*h^2)
// log2(e) folded so we use raw v_exp_f32 (exp2):
__device__ __forceinline__ float fast_gelu(float h) {
    float p  = h * h;
    float u2 = h * (2.3022164464f + 0.1029435704f * p);
    float e  = __builtin_amdgcn_exp2f(u2);
    float r  = __builtin_amdgcn_rcpf(e + 1.0f);
    return h - h * r;
}

// ---- pre-pass: W2[j][l][m] (fp32) -> W2t[j][m][l] (f16), per 64x64 tile ----
__global__ __launch_bounds__(256) void transpose_w2(
    const float* __restrict__ W2_3, const float* __restrict__ W2_2,
    const float* __restrict__ W2_1, _Float16* __restrict__ W2t)
{
    __shared__ float tile[64][65];
    const int bid = blockIdx.x;
    const int j   = bid >> 4;          // 16 tiles per joint
    const int t   = bid & 15;
    const int l0  = (t >> 2) * 64;
    const int m0  = (t & 3) * 64;

    const float* W2 = (j < NJ3) ? (W2_3 + (size_t)j * 65536)
                    : (j < NJ3 + NJ2) ? (W2_2 + (size_t)(j - NJ3) * 65536)
                    : (W2_1 + (size_t)(j - NJ3 - NJ2) * 65536);

    const int tx = threadIdx.x & 15, ty = threadIdx.x >> 4;
#pragma unroll
    for (int rr = 0; rr < 4; ++rr) {
        const int row = ty + rr * 16;
        const float4 v = *(const float4*)(W2 + (size_t)(l0 + row) * 256 + m0 + tx * 4);
        tile[row][tx * 4 + 0] = v.x;
        tile[row][tx * 4 + 1] = v.y;
        tile[row][tx * 4 + 2] = v.z;
        tile[row][tx * 4 + 3] = v.w;
    }
    __syncthreads();
#pragma unroll
    for (int rr = 0; rr < 4; ++rr) {
        const int mrow = ty + rr * 16;
        const int ll   = tx * 4;
        half4v o;
        o[0] = (_Float16)tile[ll + 0][mrow];
        o[1] = (_Float16)tile[ll + 1][mrow];
        o[2] = (_Float16)tile[ll + 2][mrow];
        o[3] = (_Float16)tile[ll + 3][mrow];
        *(half4v*)(W2t + ((size_t)j * 256 + m0 + mrow) * 256 + l0 + ll) = o;
    }
}

// ---- fused main kernel: per block = (joint j, 64-row tile) ----
// RESTRUCTURED this round around the LDS-serialization theory (r5 showed
// 2.67x occupancy = null -> CU-serialized resource; LDS op count was 69
// b128/thread ~= 45 us CU-serialized):
//  * ONE-PASS A: all of A (64 rows x 256 l, f16) computed once into a
//    single 32 KB LDS buffer. h-phase role: lane = row, wave wv owns
//    l-slice [wv*32, wv*32+32) -> W1s/b1s reads are WAVE-UNIFORM
//    broadcasts (free per m136) instead of 64-distinct full-rate reads.
//  * MFMA phase re-tiled 2M x 4N (wave = 32 rows x 64 cols): af reads
//    32 -> 16 b128/thread (A re-read 2x per block, was 8x); bf VMEM
//    16 -> 32 (B L2-traffic 2x -- rebalance onto the idle L2 pipe).
//    Phase is barrier-free (A read-only after one __syncthreads).
//  * Barriers 6 -> 2 total. Distinct-unit LDS ops ~69 -> ~20/thread.
// Unchanged: swapped mfma(bf,af) -> float4 nt row-stores; bijective XCD
// swizzle; s_setprio around MFMA; (512,4) = 8 waves/SIMD, 4 blocks/CU
// (LDS 36.5 KB -> 4 blocks = 146 KB < 160 KB).
__global__ __launch_bounds__(512, 4) void motion_main(
    const float* __restrict__ x,
    const float* __restrict__ W1_3, const float* __restrict__ b1_3, const float* __restrict__ b2_3,
    const float* __restrict__ W1_2, const float* __restrict__ b1_2, const float* __restrict__ b2_2,
    const float* __restrict__ W1_1, const float* __restrict__ b1_1, const float* __restrict__ b2_1,
    const _Float16* __restrict__ W2t,
    float* __restrict__ out)
{
    // A2[(i*32 + kq)*16 + m] = h[i*16+m][kq*8 .. +8], i=row/16, kq=l/8
    __shared__ half8 A2[2048];         // 4*32*16 x 16B = 32 KB
    __shared__ float W1s[3 * 256];     // 3 KB (absent rows alias row0; xv=0 kills them)
    __shared__ float b1s[256];         // 1 KB

    // bijective XCD swizzle (m204 formula; NWG=4214 not divisible by 8)
    const int orig = blockIdx.x;
    const int q8   = NWG >> 3, r8 = NWG & 7;
    const int xcd  = orig & 7;
    const int wgid = (xcd < r8 ? xcd * (q8 + 1)
                               : r8 * (q8 + 1) + (xcd - r8) * q8) + (orig >> 3);

    const int j   = wgid / 98;         // m-tile fastest -> same-j blocks adjacent
    const int mt  = wgid % 98;
    const int r0  = mt * 64;

    int d, xoff;
    const float *W1, *b1, *b2;
    if (j < NJ3)            { d = 3; xoff = j * 3;
                              W1 = W1_3 + j * 768;  b1 = b1_3 + j * 256;  b2 = b2_3 + j * 256; }
    else if (j < NJ3 + NJ2) { const int qj = j - NJ3; d = 2; xoff = D3 + qj * 2;
                              W1 = W1_2 + qj * 512;  b1 = b1_2 + qj * 256;  b2 = b2_2 + qj * 256; }
    else                    { const int qj = j - NJ3 - NJ2; d = 1; xoff = D3 + D2 + qj;
                              W1 = W1_1 + qj * 256;  b1 = b1_1 + qj * 256;  b2 = b2_1 + qj * 256; }

    const int tid  = threadIdx.x;
    const int lane = tid & 63;
    const int wv   = tid >> 6;         // wave id 0..7
    const int m16  = lane & 15;
    const int quad = lane >> 4;

    // branch-free W1 row pointers: absent rows alias row 0 and multiply by 0
    const float* W1r0 = W1;
    const float* W1r1 = W1 + ((d > 1) ? 256 : 0);
    const float* W1r2 = W1 + ((d > 2) ? 512 : 0);

    // ---- stage W1 (3 rows) + b1 into LDS, coalesced float4 ----
    if (tid < 192) {
        const float* src = (tid < 64) ? W1r0 : (tid < 128) ? W1r1 : W1r2;
        const int o = (tid & 63) * 4;
        *(float4*)(W1s + (tid >> 6) * 256 + o) = *(const float4*)(src + o);
    } else if (tid < 256) {
        const int o = (tid - 192) * 4;
        *(float4*)(b1s + o) = *(const float4*)(b1 + o);
    }

    // ---- h-phase inputs: lane = row; this wave computes l in [wvu*32, +32) ----
    const int wvu = __builtin_amdgcn_readfirstlane(wv);   // provably uniform
    const float* xr  = x + (size_t)(r0 + lane) * XDIM + xoff;
    const float  xv0 = xr[0];
    const float  xv1 = (d > 1) ? xr[1] : 0.0f;
    const float  xv2 = (d > 2) ? xr[2] : 0.0f;

    __syncthreads();                   // W1s/b1s visible

    // ---- one-pass h-phase: 4 octets of l per wave; uniform-addr broadcasts ----
    {
        const int i = lane >> 4, m = lane & 15;
#pragma unroll
        for (int t = 0; t < 4; ++t) {
            const int l0 = wvu * 32 + t * 8;   // wave-uniform
            float h[8];
#pragma unroll
            for (int u = 0; u < 8; ++u) h[u] = b1s[l0 + u];
#pragma unroll
            for (int u = 0; u < 8; ++u) h[u] += xv0 * W1s[l0 + u];
#pragma unroll
            for (int u = 0; u < 8; ++u) h[u] += xv1 * W1s[256 + l0 + u];
#pragma unroll
            for (int u = 0; u < 8; ++u) h[u] += xv2 * W1s[512 + l0 + u];
            half8 v;
#pragma unroll
            for (int u = 0; u < 8; ++u) v[u] = (_Float16)fast_gelu(h[u]);
            const int kq = wvu * 4 + t;
            A2[(i * 32 + kq) * 16 + m] = v;    // 64 distinct 16B units/inst
        }
    }
    __syncthreads();                   // A2 complete; no more barriers

    // ---- MFMA phase: wave = 32 rows x 64 cols (2M x 4N) ----
    const int Mg = wv >> 2;            // 0..1: 32-row group
    const int Nq = wv & 3;             // 0..3: 64-col group
    const _Float16* W2j = W2t + (size_t)j * 65536 + (size_t)(Nq * 64) * 256;

    floatx4 acc[2][4];
#pragma unroll
    for (int i2 = 0; i2 < 2; ++i2)
#pragma unroll
        for (int jj = 0; jj < 4; ++jj)
            acc[i2][jj] = (floatx4){0.f, 0.f, 0.f, 0.f};

    for (int kc = 0; kc < 4; ++kc) {
#pragma unroll
        for (int kk2 = 0; kk2 < 2; ++kk2) {
            half8 af[2];
#pragma unroll
            for (int i2 = 0; i2 < 2; ++i2)
                af[i2] = A2[((Mg * 2 + i2) * 32 + kc * 8 + kk2 * 4 + quad) * 16 + m16];
            const int kidx = kc * 64 + kk2 * 32 + quad * 8;
            __builtin_amdgcn_s_setprio(1);
#pragma unroll
            for (int jj = 0; jj < 4; ++jj) {
                const half8 bf = *(const half8*)(W2j + (size_t)(jj * 16 + m16) * 256 + kidx);
                acc[0][jj] = __builtin_amdgcn_mfma_f32_16x16x32_f16(bf, af[0], acc[0][jj], 0, 0, 0);
                acc[1][jj] = __builtin_amdgcn_mfma_f32_16x16x32_f16(bf, af[1], acc[1][jj], 0, 0, 0);
            }
            __builtin_amdgcn_s_setprio(0);
        }
    }

    // ---- epilogue: +b2, nontemporal floatx4 stores ----
    // swapped-D layout: reg g holds out[r0+Mg*32+i2*16+m16][Nq*64+jj*16+quad*4+g]
    floatx4 b2q[4];
#pragma unroll
    for (int jj = 0; jj < 4; ++jj)
        b2q[jj] = *(const floatx4*)(b2 + Nq * 64 + jj * 16 + quad * 4);

    const size_t colbase = (size_t)j * 256 + Nq * 64 + quad * 4;
#pragma unroll
    for (int i2 = 0; i2 < 2; ++i2) {
        float* orow = out + (size_t)(r0 + Mg * 32 + i2 * 16 + m16) * OUTROW + colbase;
#pragma unroll
        for (int jj = 0; jj < 4; ++jj) {
            floatx4 v = acc[i2][jj] + b2q[jj];
            __builtin_nontemporal_store(v, (floatx4*)(orow + jj * 16));
        }
    }
}

extern "C" void kernel_launch(void* const* d_in, const int* in_sizes, int n_in,
                              void* d_out, int out_size, void* d_ws, size_t ws_size,
                              hipStream_t stream) {
    const float* x    = (const float*)d_in[0];
    const float* W1_3 = (const float*)d_in[1];
    const float* b1_3 = (const float*)d_in[2];
    const float* W2_3 = (const float*)d_in[3];
    const float* b2_3 = (const float*)d_in[4];
    const float* W1_2 = (const float*)d_in[5];
    const float* b1_2 = (const float*)d_in[6];
    const float* W2_2 = (const float*)d_in[7];
    const float* b2_2 = (const float*)d_in[8];
    const float* W1_1 = (const float*)d_in[9];
    const float* b1_1 = (const float*)d_in[10];
    const float* W2_1 = (const float*)d_in[11];
    const float* b2_1 = (const float*)d_in[12];
    float* out = (float*)d_out;
    _Float16* W2t = (_Float16*)d_ws;   // 43*256*256 f16 = 5.64 MB, rebuilt every call

    transpose_w2<<<NJ * 16, 256, 0, stream>>>(W2_3, W2_2, W2_1, W2t);
    motion_main<<<NWG, 512, 0, stream>>>(x, W1_3, b1_3, b2_3,
                                         W1_2, b1_2, b2_2,
                                         W1_1, b1_1, b2_1, W2t, out);
}